// Round 2
// baseline (11101.865 us; speedup 1.0000x reference)
//
#include <hip/hip_runtime.h>

// Problem constants (fixed by the reference).
static constexpr int NODES  = 5000000;   // N
static constexpr int EDGES  = 80000000;  // E
static constexpr int GRAPHS = 100000;    // NUM_GRAPHS
static constexpr int NPG    = 50;        // NODES_PER_GRAPH

// Binning parameters.
static constexpr int NB    = 40;         // buckets; 40 % 8 == 0 -> bucket pins to one XCD
static constexpr int SHIFT = 17;         // bucket = node >> 17 (window 131072 nodes = 512KB)
static constexpr int CAP   = 2200000;    // per-bucket capacity (expected max 2.10M, sigma ~1.5K)
static constexpr int TILE  = 4096;       // edges per block-tile (256 thr x 16)
static constexpr int EPT   = 16;         // edges per thread per tile
static constexpr int BPB   = 16;         // blocks per bucket in bucket-phase kernels

// ---------------------------------------------------------------------------
// Pass 1: dual multisplit. One streaming read of (row,col); write (row,col)
// binned by row (for the L2-local s gather later) and col binned by col (for
// the L2-local degree histogram). Two-phase LDS ranking gives each tile
// contiguous runs per bucket (~100 entries) so the scattered writes stay
// mostly line-coalesced.
// ---------------------------------------------------------------------------
__global__ void __launch_bounds__(256) k_bin(const int* __restrict__ row,
                                             const int* __restrict__ col,
                                             int* __restrict__ gc1,
                                             int* __restrict__ gc2,
                                             int* __restrict__ b1row,
                                             int* __restrict__ b1col,
                                             int* __restrict__ b2col) {
    __shared__ int rc1[NB], rc2[NB], sb1[NB], sb2[NB];
    const int tid = threadIdx.x;
    const int base = blockIdx.x * TILE;
    if (tid < NB) { rc1[tid] = 0; rc2[tid] = 0; }
    __syncthreads();

    int r[EPT], c[EPT], m1[EPT], m2[EPT];
    #pragma unroll
    for (int k = 0; k < EPT; ++k) {
        int j = base + k * 256 + tid;
        if (j < EDGES) { r[k] = row[j]; c[k] = col[j]; }
        else           { r[k] = -1; c[k] = 0; }
    }
    #pragma unroll
    for (int k = 0; k < EPT; ++k) {
        if (r[k] >= 0) {
            int b  = r[k] >> SHIFT;
            m1[k] = (atomicAdd(&rc1[b], 1) << 6) | b;
            int b2 = c[k] >> SHIFT;
            m2[k] = (atomicAdd(&rc2[b2], 1) << 6) | b2;
        } else { m1[k] = -1; m2[k] = -1; }
    }
    __syncthreads();
    if (tid < NB) {
        sb1[tid] = atomicAdd(&gc1[tid], rc1[tid]);
        sb2[tid] = atomicAdd(&gc2[tid], rc2[tid]);
    }
    __syncthreads();
    #pragma unroll
    for (int k = 0; k < EPT; ++k) {
        if (m1[k] >= 0) {
            int b   = m1[k] & 63;
            int pos = b * CAP + sb1[b] + (m1[k] >> 6);
            b1row[pos] = r[k];
            b1col[pos] = c[k];
            int b2   = m2[k] & 63;
            int pos2 = b2 * CAP + sb2[b2] + (m2[k] >> 6);
            b2col[pos2] = c[k];
        }
    }
}

// ---------------------------------------------------------------------------
// Pass 2: degree histogram from col-binned stream. Atomics land in a 512KB
// window pinned (via bid % NB, NB % 8 == 0) to one XCD's L2.
// ---------------------------------------------------------------------------
__global__ void __launch_bounds__(256) k_degb(const int* __restrict__ gc2,
                                              const int* __restrict__ b2col,
                                              float* __restrict__ deg) {
    const int b     = blockIdx.x % NB;
    const int slice = blockIdx.x / NB;
    const int n     = gc2[b];
    const int chunk = (n + BPB - 1) / BPB;
    const int start = slice * chunk;
    const int end   = min(n, start + chunk);
    const int* p = b2col + (size_t)b * CAP;
    for (int j = start + threadIdx.x; j < end; j += 256)
        atomicAdd(&deg[p[j]], 1.0f);
}

// ---------------------------------------------------------------------------
// Pass 3: per-node source weight s[i] = x[i]*w * rsqrt(deg[i]+1).
// ---------------------------------------------------------------------------
__global__ void __launch_bounds__(256) k_scale(const float4* __restrict__ x4,
                                               const float4* __restrict__ deg4,
                                               const float* __restrict__ conv_w,
                                               float4* __restrict__ s4) {
    int i = blockIdx.x * 256 + threadIdx.x;
    if (i < NODES / 4) {
        float w = conv_w[0];
        float4 x = x4[i];
        float4 d = deg4[i];
        float4 s;
        s.x = x.x * w * rsqrtf(d.x + 1.0f);
        s.y = x.y * w * rsqrtf(d.y + 1.0f);
        s.z = x.z * w * rsqrtf(d.z + 1.0f);
        s.w = x.w * w * rsqrtf(d.w + 1.0f);
        s4[i] = s;
    }
}

// ---------------------------------------------------------------------------
// Pass 4: per row-bucket, gather s[row] from the L2-hot 512KB window and
// re-bin (val, col) by col for the final accumulation. Same two-phase
// multisplit as k_bin.
// ---------------------------------------------------------------------------
__global__ void __launch_bounds__(256) k_rebin(const int* __restrict__ gc1,
                                               const int* __restrict__ b1row,
                                               const int* __restrict__ b1col,
                                               const float* __restrict__ s,
                                               int* __restrict__ gc3,
                                               float* __restrict__ b3val,
                                               int* __restrict__ b3col) {
    __shared__ int rc[NB], sb[NB];
    const int tid   = threadIdx.x;
    const int b     = blockIdx.x % NB;
    const int slice = blockIdx.x / NB;
    const int n     = gc1[b];
    const int chunk = (n + BPB - 1) / BPB;
    const int start = slice * chunk;
    const int end   = min(n, start + chunk);
    const int* prow = b1row + (size_t)b * CAP;
    const int* pcol = b1col + (size_t)b * CAP;

    for (int t0 = start; t0 < end; t0 += TILE) {
        if (tid < NB) rc[tid] = 0;
        __syncthreads();
        float v[EPT]; int c[EPT], m[EPT];
        #pragma unroll
        for (int k = 0; k < EPT; ++k) {
            int j = t0 + k * 256 + tid;
            if (j < end) {
                int rr = prow[j];
                c[k]   = pcol[j];
                v[k]   = s[rr];                    // L2-hot window
                int bb = c[k] >> SHIFT;
                m[k]   = (atomicAdd(&rc[bb], 1) << 6) | bb;
            } else { m[k] = -1; v[k] = 0.0f; c[k] = 0; }
        }
        __syncthreads();
        if (tid < NB) sb[tid] = atomicAdd(&gc3[tid], rc[tid]);
        __syncthreads();
        #pragma unroll
        for (int k = 0; k < EPT; ++k) {
            if (m[k] >= 0) {
                int bb  = m[k] & 63;
                int pos = bb * CAP + sb[bb] + (m[k] >> 6);
                b3val[pos] = v[k];
                b3col[pos] = c[k];
            }
        }
        __syncthreads();   // rc reused next tile
    }
}

// ---------------------------------------------------------------------------
// Pass 5: t[col] += val from col-binned stream. Atomics hit a 512KB t-window
// pinned to one XCD's L2.
// ---------------------------------------------------------------------------
__global__ void __launch_bounds__(256) k_accum(const int* __restrict__ gc3,
                                               const float* __restrict__ b3val,
                                               const int* __restrict__ b3col,
                                               float* __restrict__ t) {
    const int b     = blockIdx.x % NB;
    const int slice = blockIdx.x / NB;
    const int n     = gc3[b];
    const int chunk = (n + BPB - 1) / BPB;
    const int start = slice * chunk;
    const int end   = min(n, start + chunk);
    const float* pv = b3val + (size_t)b * CAP;
    const int*   pc = b3col + (size_t)b * CAP;
    for (int j = start + threadIdx.x; j < end; j += 256)
        atomicAdd(&t[pc[j]], pv[j]);
}

// ---------------------------------------------------------------------------
// Pass 6: epilogue. h[i] = dis[i]*t[i] + xw[i]/deg_tot[i] + conv_b, then the
// per-graph 50->2 FC. One thread per graph.
// ---------------------------------------------------------------------------
__global__ void __launch_bounds__(256) k_final(const float* __restrict__ x,
                                               const float* __restrict__ deg,
                                               const float* __restrict__ t,
                                               const float* __restrict__ conv_w,
                                               const float* __restrict__ conv_b,
                                               const float* __restrict__ fc_w,
                                               const float* __restrict__ fc_b,
                                               float* __restrict__ out) {
    int g = blockIdx.x * 256 + threadIdx.x;
    if (g >= GRAPHS) return;
    float w = conv_w[0];
    float b = conv_b[0];
    float acc0 = 0.0f, acc1 = 0.0f;
    int base = g * NPG;
    #pragma unroll 5
    for (int j = 0; j < NPG; ++j) {
        float d   = deg[base + j] + 1.0f;     // includes self-loop
        float dis = rsqrtf(d);
        float xw  = x[base + j] * w;
        float h   = dis * t[base + j] + xw / d + b;
        acc0 += h * fc_w[j];
        acc1 += h * fc_w[NPG + j];
    }
    out[g * 2 + 0] = acc0 + fc_b[0];
    out[g * 2 + 1] = acc1 + fc_b[1];
}

// --------------------------- fallback path (round-1) -----------------------
__global__ void __launch_bounds__(256) k_deg_naive(const int4* __restrict__ col4,
                                                   float* __restrict__ deg) {
    int i = blockIdx.x * 256 + threadIdx.x;
    if (i < EDGES / 4) {
        int4 c = col4[i];
        atomicAdd(&deg[c.x], 1.0f);
        atomicAdd(&deg[c.y], 1.0f);
        atomicAdd(&deg[c.z], 1.0f);
        atomicAdd(&deg[c.w], 1.0f);
    }
}

__global__ void __launch_bounds__(256) k_scatter_naive(const int4* __restrict__ row4,
                                                       const int4* __restrict__ col4,
                                                       const float* __restrict__ s,
                                                       float* __restrict__ t) {
    int i = blockIdx.x * 256 + threadIdx.x;
    if (i < EDGES / 4) {
        int4 r = row4[i];
        int4 c = col4[i];
        atomicAdd(&t[c.x], s[r.x]);
        atomicAdd(&t[c.y], s[r.y]);
        atomicAdd(&t[c.z], s[r.z]);
        atomicAdd(&t[c.w], s[r.w]);
    }
}

extern "C" void kernel_launch(void* const* d_in, const int* in_sizes, int n_in,
                              void* d_out, int out_size, void* d_ws, size_t ws_size,
                              hipStream_t stream) {
    const float* x      = (const float*)d_in[0];   // [N,1]
    const int*   ei     = (const int*)  d_in[1];   // [2,E]: row then col
    const float* conv_w = (const float*)d_in[2];
    const float* conv_b = (const float*)d_in[3];
    const float* fc_w   = (const float*)d_in[4];   // [2,50]
    const float* fc_b   = (const float*)d_in[5];
    float* out = (float*)d_out;                    // [G,2]

    const int* row = ei;
    const int* col = ei + EDGES;

    // Workspace layout:
    // [gc1|gc2|gc3 pad to 1KB][deg 20MB][t 20MB][s 20MB][B1row 352MB][B1col 352MB]
    // [region2 704MB: B2col (first half) reused as B3val; B3col second half]
    int*   gc1 = (int*)d_ws;
    int*   gc2 = gc1 + 64;
    int*   gc3 = gc2 + 64;
    float* deg = (float*)((char*)d_ws + 1024);
    float* t   = deg + NODES;
    float* s   = t + NODES;
    int*   b1row = (int*)(s + NODES);
    int*   b1col = b1row + (size_t)NB * CAP;
    int*   b2col = b1col + (size_t)NB * CAP;   // region2
    float* b3val = (float*)b2col;              // overlaps b2col (consumed by then)
    int*   b3col = b2col + (size_t)NB * CAP;

    const size_t needed = 1024 + 3ull * NODES * 4 + 4ull * NB * CAP * 4;

    int nblocks = (NODES / 4 + 255) / 256;
    int gblocks = (GRAPHS + 255) / 256;

    if (ws_size >= needed) {
        // zero counters + deg + t (contiguous at workspace start)
        hipMemsetAsync(d_ws, 0, 1024 + 2ull * NODES * 4, stream);
        int binblocks = (EDGES + TILE - 1) / TILE;
        k_bin<<<binblocks, 256, 0, stream>>>(row, col, gc1, gc2, b1row, b1col, b2col);
        k_degb<<<NB * BPB, 256, 0, stream>>>(gc2, b2col, deg);
        k_scale<<<nblocks, 256, 0, stream>>>((const float4*)x, (const float4*)deg,
                                             conv_w, (float4*)s);
        k_rebin<<<NB * BPB, 256, 0, stream>>>(gc1, b1row, b1col, s, gc3, b3val, b3col);
        k_accum<<<NB * BPB, 256, 0, stream>>>(gc3, b3val, b3col, t);
        k_final<<<gblocks, 256, 0, stream>>>(x, deg, t, conv_w, conv_b, fc_w, fc_b, out);
    } else {
        // round-1 fallback (ws too small for binning)
        float* fdeg = (float*)d_ws;
        float* ft   = fdeg + NODES;
        float* fs   = ft + NODES;
        hipMemsetAsync(d_ws, 0, 2ull * NODES * sizeof(float), stream);
        int eblocks = (EDGES / 4 + 255) / 256;
        k_deg_naive<<<eblocks, 256, 0, stream>>>((const int4*)col, fdeg);
        k_scale<<<nblocks, 256, 0, stream>>>((const float4*)x, (const float4*)fdeg,
                                             conv_w, (float4*)fs);
        k_scatter_naive<<<eblocks, 256, 0, stream>>>((const int4*)row, (const int4*)col,
                                                     fs, ft);
        k_final<<<gblocks, 256, 0, stream>>>(x, fdeg, ft, conv_w, conv_b, fc_w, fc_b, out);
    }
}

// Round 3
// 3757.483 us; speedup vs baseline: 2.9546x; 2.9546x over previous
//
#include <hip/hip_runtime.h>

// Problem constants (fixed by the reference).
static constexpr int NODES  = 5000000;   // N
static constexpr int EDGES  = 80000000;  // E
static constexpr int GRAPHS = 100000;    // NUM_GRAPHS
static constexpr int NPG    = 50;        // NODES_PER_GRAPH

// Binning parameters.
static constexpr int W      = 16384;     // nodes per bucket window (64 KB LDS of floats)
static constexpr int WSHIFT = 14;        // bucket = node >> 14
static constexpr int NBC    = 306;       // ceil(NODES / W)
static constexpr int CAP    = 266240;    // per-bucket capacity (mean 261438, sigma ~511)
static constexpr int BINT   = 512;       // k_bin block size
static constexpr int EPT    = 32;        // edges per thread in k_bin
static constexpr int TILE   = BINT * EPT; // 16384 edges per k_bin block
static constexpr int BPB    = 4;         // slices per bucket in LDS-accum kernels

// ---------------------------------------------------------------------------
// Pass 1: multisplit (row,col) by col-bucket. Two-phase LDS ranking gives
// each bucket a contiguous run (~53 edges) per tile so scattered writes stay
// mostly line-coalesced. NO global atomics except one per (block,bucket).
// ---------------------------------------------------------------------------
__global__ void __launch_bounds__(512) k_bin(const int* __restrict__ row,
                                             const int* __restrict__ col,
                                             int* __restrict__ gc,
                                             int* __restrict__ brow,
                                             int* __restrict__ bcol) {
    __shared__ int rc[NBC], sb[NBC];
    const int tid  = threadIdx.x;
    const int base = blockIdx.x * TILE;
    for (int i = tid; i < NBC; i += BINT) rc[i] = 0;
    __syncthreads();

    int r[EPT], c[EPT], m[EPT];
    #pragma unroll
    for (int k = 0; k < EPT; ++k) {
        int j = base + k * BINT + tid;
        if (j < EDGES) { r[k] = row[j]; c[k] = col[j]; }
        else           { r[k] = -1; c[k] = 0; }
    }
    #pragma unroll
    for (int k = 0; k < EPT; ++k) {
        if (r[k] >= 0) {
            int b = c[k] >> WSHIFT;                      // 0..305 (9 bits)
            m[k] = (atomicAdd(&rc[b], 1) << 9) | b;      // rank<<9 | bucket
        } else m[k] = -1;
    }
    __syncthreads();
    for (int i = tid; i < NBC; i += BINT)
        sb[i] = rc[i] ? atomicAdd(&gc[i], rc[i]) : 0;
    __syncthreads();
    #pragma unroll
    for (int k = 0; k < EPT; ++k) {
        if (m[k] >= 0) {
            int b   = m[k] & 511;
            int pos = b * CAP + sb[b] + (m[k] >> 9);
            brow[pos] = r[k];
            bcol[pos] = c[k];
        }
    }
}

// ---------------------------------------------------------------------------
// Pass 2: degree histogram via LDS atomics. Block (bucket b, slice sl)
// accumulates its chunk into a private 64KB LDS window, then plain-stores the
// window into slab slice sl. Zero global atomics.
// ---------------------------------------------------------------------------
__global__ void __launch_bounds__(256) k_hist(const int* __restrict__ gc,
                                              const int* __restrict__ bcol,
                                              float* __restrict__ slab) {
    __shared__ float win[W];
    const int b     = blockIdx.x % NBC;
    const int sl    = blockIdx.x / NBC;
    const int n     = min(gc[b], CAP);
    const int chunk = (n + BPB - 1) / BPB;
    const int start = sl * chunk;
    const int end   = min(n, start + chunk);
    for (int i = threadIdx.x; i < W; i += 256) win[i] = 0.0f;
    __syncthreads();
    const int* p = bcol + (size_t)b * CAP;
    const int basenode = b << WSHIFT;
    for (int j = start + threadIdx.x; j < end; j += 256)
        atomicAdd(&win[p[j] - basenode], 1.0f);
    __syncthreads();
    float* dst = slab + (size_t)sl * NODES + basenode;
    const int wlen = min(W, NODES - basenode);
    for (int i = threadIdx.x; i < wlen; i += 256) dst[i] = win[i];
}

// ---------------------------------------------------------------------------
// Pass 3: deg = sum of 4 slabs; s = x*w*rsqrt(deg+1). Vectorized.
// ---------------------------------------------------------------------------
__global__ void __launch_bounds__(256) k_merge_scale(const float4* __restrict__ x4,
                                                     const float4* __restrict__ slab4,
                                                     const float* __restrict__ conv_w,
                                                     float4* __restrict__ deg4,
                                                     float4* __restrict__ s4) {
    int i = blockIdx.x * 256 + threadIdx.x;
    if (i >= NODES / 4) return;
    const int Q = NODES / 4;
    float4 d0 = slab4[i];
    float4 d1 = slab4[i + Q];
    float4 d2 = slab4[i + 2 * Q];
    float4 d3 = slab4[i + 3 * Q];
    float4 d;
    d.x = d0.x + d1.x + d2.x + d3.x;
    d.y = d0.y + d1.y + d2.y + d3.y;
    d.z = d0.z + d1.z + d2.z + d3.z;
    d.w = d0.w + d1.w + d2.w + d3.w;
    deg4[i] = d;
    float w = conv_w[0];
    float4 x = x4[i];
    float4 s;
    s.x = x.x * w * rsqrtf(d.x + 1.0f);
    s.y = x.y * w * rsqrtf(d.y + 1.0f);
    s.z = x.z * w * rsqrtf(d.z + 1.0f);
    s.w = x.w * w * rsqrtf(d.w + 1.0f);
    s4[i] = s;
}

// ---------------------------------------------------------------------------
// Pass 4: t-accumulation. Stream the bucket's (row,col); gather s[row]
// (random, IC-resident 20MB); ds_add into the LDS window; store slab slice.
// Unroll-8 batches the gathers for memory-level parallelism.
// ---------------------------------------------------------------------------
__global__ void __launch_bounds__(256) k_acc(const int* __restrict__ gc,
                                             const int* __restrict__ brow,
                                             const int* __restrict__ bcol,
                                             const float* __restrict__ s,
                                             float* __restrict__ slab) {
    __shared__ float win[W];
    const int b     = blockIdx.x % NBC;
    const int sl    = blockIdx.x / NBC;
    const int n     = min(gc[b], CAP);
    const int chunk = (n + BPB - 1) / BPB;
    const int start = sl * chunk;
    const int end   = min(n, start + chunk);
    for (int i = threadIdx.x; i < W; i += 256) win[i] = 0.0f;
    __syncthreads();
    const int* pr = brow + (size_t)b * CAP;
    const int* pc = bcol + (size_t)b * CAP;
    const int basenode = b << WSHIFT;

    constexpr int U = 8;
    int j = start + threadIdx.x;
    for (; j + 256 * (U - 1) < end; j += 256 * U) {
        int rr[U], cc[U];
        float v[U];
        #pragma unroll
        for (int k = 0; k < U; ++k) { rr[k] = pr[j + 256 * k]; cc[k] = pc[j + 256 * k]; }
        #pragma unroll
        for (int k = 0; k < U; ++k) v[k] = s[rr[k]];
        #pragma unroll
        for (int k = 0; k < U; ++k) atomicAdd(&win[cc[k] - basenode], v[k]);
    }
    for (; j < end; j += 256)
        atomicAdd(&win[pc[j] - basenode], s[pr[j]]);
    __syncthreads();
    float* dst = slab + (size_t)sl * NODES + basenode;
    const int wlen = min(W, NODES - basenode);
    for (int i = threadIdx.x; i < wlen; i += 256) dst[i] = win[i];
}

// ---------------------------------------------------------------------------
// Pass 5: fused t-merge + epilogue + 50->2 FC. One thread per graph.
// ---------------------------------------------------------------------------
__global__ void __launch_bounds__(256) k_final(const float* __restrict__ x,
                                               const float* __restrict__ deg,
                                               const float* __restrict__ slab,
                                               const float* __restrict__ conv_w,
                                               const float* __restrict__ conv_b,
                                               const float* __restrict__ fc_w,
                                               const float* __restrict__ fc_b,
                                               float* __restrict__ out) {
    int g = blockIdx.x * 256 + threadIdx.x;
    if (g >= GRAPHS) return;
    float w = conv_w[0];
    float b = conv_b[0];
    float acc0 = 0.0f, acc1 = 0.0f;
    int base = g * NPG;
    #pragma unroll 5
    for (int j = 0; j < NPG; ++j) {
        int i = base + j;
        float tv = slab[i] + slab[i + NODES] + slab[i + 2 * NODES] + slab[i + 3 * NODES];
        float d  = deg[i] + 1.0f;             // includes self-loop
        float h  = rsqrtf(d) * tv + x[i] * w / d + b;
        acc0 += h * fc_w[j];
        acc1 += h * fc_w[NPG + j];
    }
    out[g * 2 + 0] = acc0 + fc_b[0];
    out[g * 2 + 1] = acc1 + fc_b[1];
}

// --------------------------- fallback path (round-1) -----------------------
__global__ void __launch_bounds__(256) k_deg_naive(const int4* __restrict__ col4,
                                                   float* __restrict__ deg) {
    int i = blockIdx.x * 256 + threadIdx.x;
    if (i < EDGES / 4) {
        int4 c = col4[i];
        atomicAdd(&deg[c.x], 1.0f);
        atomicAdd(&deg[c.y], 1.0f);
        atomicAdd(&deg[c.z], 1.0f);
        atomicAdd(&deg[c.w], 1.0f);
    }
}

__global__ void __launch_bounds__(256) k_scale_naive(const float4* __restrict__ x4,
                                                     const float4* __restrict__ deg4,
                                                     const float* __restrict__ conv_w,
                                                     float4* __restrict__ s4) {
    int i = blockIdx.x * 256 + threadIdx.x;
    if (i < NODES / 4) {
        float w = conv_w[0];
        float4 x = x4[i];
        float4 d = deg4[i];
        float4 s;
        s.x = x.x * w * rsqrtf(d.x + 1.0f);
        s.y = x.y * w * rsqrtf(d.y + 1.0f);
        s.z = x.z * w * rsqrtf(d.z + 1.0f);
        s.w = x.w * w * rsqrtf(d.w + 1.0f);
        s4[i] = s;
    }
}

__global__ void __launch_bounds__(256) k_scatter_naive(const int4* __restrict__ row4,
                                                       const int4* __restrict__ col4,
                                                       const float* __restrict__ s,
                                                       float* __restrict__ t) {
    int i = blockIdx.x * 256 + threadIdx.x;
    if (i < EDGES / 4) {
        int4 r = row4[i];
        int4 c = col4[i];
        atomicAdd(&t[c.x], s[r.x]);
        atomicAdd(&t[c.y], s[r.y]);
        atomicAdd(&t[c.z], s[r.z]);
        atomicAdd(&t[c.w], s[r.w]);
    }
}

__global__ void __launch_bounds__(256) k_final_naive(const float* __restrict__ x,
                                                     const float* __restrict__ deg,
                                                     const float* __restrict__ t,
                                                     const float* __restrict__ conv_w,
                                                     const float* __restrict__ conv_b,
                                                     const float* __restrict__ fc_w,
                                                     const float* __restrict__ fc_b,
                                                     float* __restrict__ out) {
    int g = blockIdx.x * 256 + threadIdx.x;
    if (g >= GRAPHS) return;
    float w = conv_w[0];
    float b = conv_b[0];
    float acc0 = 0.0f, acc1 = 0.0f;
    int base = g * NPG;
    #pragma unroll 5
    for (int j = 0; j < NPG; ++j) {
        float d   = deg[base + j] + 1.0f;
        float h   = rsqrtf(d) * t[base + j] + x[base + j] * w / d + b;
        acc0 += h * fc_w[j];
        acc1 += h * fc_w[NPG + j];
    }
    out[g * 2 + 0] = acc0 + fc_b[0];
    out[g * 2 + 1] = acc1 + fc_b[1];
}

extern "C" void kernel_launch(void* const* d_in, const int* in_sizes, int n_in,
                              void* d_out, int out_size, void* d_ws, size_t ws_size,
                              hipStream_t stream) {
    const float* x      = (const float*)d_in[0];   // [N,1]
    const int*   ei     = (const int*)  d_in[1];   // [2,E]: row then col
    const float* conv_w = (const float*)d_in[2];
    const float* conv_b = (const float*)d_in[3];
    const float* fc_w   = (const float*)d_in[4];   // [2,50]
    const float* fc_b   = (const float*)d_in[5];
    float* out = (float*)d_out;                    // [G,2]

    const int* row = ei;
    const int* col = ei + EDGES;

    // Workspace layout:
    // [gc 4KB][deg 20MB][s 20MB][slab 4x20MB][brow 326MB][bcol 326MB] ~= 777MB
    int*   gc   = (int*)d_ws;
    float* deg  = (float*)((char*)d_ws + 4096);
    float* s    = deg + NODES;
    float* slab = s + NODES;
    int*   brow = (int*)(slab + 4ull * NODES);
    int*   bcol = brow + (size_t)NBC * CAP;

    const size_t needed = 4096 + 6ull * NODES * 4 + 2ull * NBC * CAP * 4;

    int nblocks = (NODES / 4 + 255) / 256;
    int gblocks = (GRAPHS + 255) / 256;

    if (ws_size >= needed) {
        hipMemsetAsync(gc, 0, 4096, stream);   // only the counters need zeroing
        int binblocks = (EDGES + TILE - 1) / TILE;
        k_bin<<<binblocks, BINT, 0, stream>>>(row, col, gc, brow, bcol);
        k_hist<<<NBC * BPB, 256, 0, stream>>>(gc, bcol, slab);
        k_merge_scale<<<nblocks, 256, 0, stream>>>((const float4*)x, (const float4*)slab,
                                                   conv_w, (float4*)deg, (float4*)s);
        k_acc<<<NBC * BPB, 256, 0, stream>>>(gc, brow, bcol, s, slab);
        k_final<<<gblocks, 256, 0, stream>>>(x, deg, slab, conv_w, conv_b, fc_w, fc_b, out);
    } else {
        // round-1 fallback (ws too small for binning)
        float* fdeg = (float*)d_ws;
        float* ft   = fdeg + NODES;
        float* fs   = ft + NODES;
        hipMemsetAsync(d_ws, 0, 2ull * NODES * sizeof(float), stream);
        int eblocks = (EDGES / 4 + 255) / 256;
        k_deg_naive<<<eblocks, 256, 0, stream>>>((const int4*)col, fdeg);
        k_scale_naive<<<nblocks, 256, 0, stream>>>((const float4*)x, (const float4*)fdeg,
                                                   conv_w, (float4*)fs);
        k_scatter_naive<<<eblocks, 256, 0, stream>>>((const int4*)row, (const int4*)col,
                                                     fs, ft);
        k_final_naive<<<gblocks, 256, 0, stream>>>(x, fdeg, ft, conv_w, conv_b,
                                                   fc_w, fc_b, out);
    }
}